// Round 3
// baseline (311.385 us; speedup 1.0000x reference)
//
#include <hip/hip_runtime.h>
#include <hip/hip_bf16.h>

typedef __bf16        bf16x8 __attribute__((ext_vector_type(8)));
typedef float         f32x16 __attribute__((ext_vector_type(16)));
typedef unsigned int  u32x4  __attribute__((ext_vector_type(4)));
typedef unsigned int   u32;
typedef unsigned short u16;

__device__ __forceinline__ u16 f32_to_bf16(float f) {
    u32 u = __builtin_bit_cast(u32, f);
    u = (u + 0x7FFFu + ((u >> 16) & 1u)) >> 16;
    return (u16)u;
}
__device__ __forceinline__ u32 pack2bf(float a, float b) {
    return (u32)f32_to_bf16(a) | ((u32)f32_to_bf16(b) << 16);
}

// ---------------- kernel 1: build conv weights, bf16, layout [tap][oc][ic]
__global__ void build_c(const float* __restrict__ wxx,
                        const float* __restrict__ wid,
                        const float* __restrict__ XX,
                        const float* __restrict__ ident,
                        const int*   __restrict__ indsxx,
                        const int*   __restrict__ indsid,
                        u16*         __restrict__ cb)
{
    int idx = blockIdx.x * 256 + threadIdx.x;          // 25*128*128 = 409600
    if (idx >= 25 * 128 * 128) return;
    int b = idx & 127;            // ic2
    int a = (idx >> 7) & 127;     // oc2
    int t = idx >> 14;            // kh*5+kw
    int w2 = (a >> 1) * 64 + (b >> 1);
    float v = wxx[w2 * 5 + indsxx[t]] * XX[(a * 128 + b) * 25 + t]
            + ident[a * 128 + b]      * wid[w2 * 6 + indsid[t]];
    cb[idx] = f32_to_bf16(v);
}

// ---------------- kernel 2: implicit-GEMM conv, 32x32x16 bf16 MFMA
// 512 thr = 8 waves (2 oc-halves x 4 w-quarters). Block: 128 oc x 4 rows x 128 w.
// Wave: 64 oc x 4 rows x 32 w -> each LDS B-chunk feeds up to 10 MFMAs (kh stencil).
__global__ void __launch_bounds__(512, 1)
conv_mfma(const float* __restrict__ x,
          const u16*   __restrict__ cb,
          float*       __restrict__ out)
{
    __shared__ u32x4 lds4[2 * 4224];                    // 2 x [8 rows][132 wp][2 chunks-swz x2]

    const int tid    = threadIdx.x;
    const int lane   = tid & 63;
    const int wv     = tid >> 6;
    const int wave_m = wv & 1;                           // oc half
    const int wave_w = wv >> 1;                          // w quarter 0..3
    const int l31    = lane & 31;
    const int h2     = lane >> 5;                        // k-half within K=16

    // bijective XCD swizzle: 512 blocks, 64 consecutive tiles per XCD
    const int bid  = blockIdx.x;
    const int sbid = (bid & 7) * 64 + (bid >> 3);
    const int bb   = sbid >> 5;                          // batch
    const int h0   = (sbid & 31) << 2;                   // output row base

    // staging mapping: thread -> (w column, ic-octet)
    const int wc     = tid & 127;                        // x column 0..127
    const int icq    = tid >> 7;                         // ic octet 0..3
    const int wp_st  = wc + 2;
    const int st_idx = (wp_st << 2) + (icq ^ ((wp_st >> 1) & 3));

    // zero halo columns wp in {0,1,130,131}, both buffers, once
    if (tid < 256) {
        const int wtab[4] = {0, 1, 130, 131};
        int bsel = tid >> 7;
        int t    = tid & 127;
        int r  = t >> 4, wq = (t >> 2) & 3, q = t & 3;
        u32x4 z = {0, 0, 0, 0};
        lds4[bsel * 4224 + r * 528 + (wtab[wq] << 2) + q] = z;
    }

    f32x16 acc[2][4];                                    // [oc 32-half][output row]
    #pragma unroll
    for (int i = 0; i < 2; ++i)
        #pragma unroll
        for (int j = 0; j < 4; ++j)
            #pragma unroll
            for (int k = 0; k < 16; ++k) acc[i][j][k] = 0.f;

    float pf[8][8];                                      // prefetch regs [row][ic]
    const float* xb = x + (bb * 128 + icq * 8) * 16384 + wc;

    auto ISSUE = [&](int ich) {
        const float* bx = xb + ich * 32 * 16384;
        #pragma unroll
        for (int r = 0; r < 8; ++r) {
            int hp = h0 - 2 + r;
            if ((unsigned)hp < 128u) {
                const float* px = bx + hp * 128;
                #pragma unroll
                for (int k = 0; k < 8; ++k) pf[r][k] = px[k * 16384];
            } else {
                #pragma unroll
                for (int k = 0; k < 8; ++k) pf[r][k] = 0.f;
            }
        }
    };

    auto WRITE = [&](u32x4* buf) {
        #pragma unroll
        for (int r = 0; r < 8; ++r) {
            u32x4 v;
            v[0] = pack2bf(pf[r][0], pf[r][1]);
            v[1] = pack2bf(pf[r][2], pf[r][3]);
            v[2] = pack2bf(pf[r][4], pf[r][5]);
            v[3] = pack2bf(pf[r][6], pf[r][7]);
            buf[r * 528 + st_idx] = v;
        }
    };

    auto COMPUTE = [&](const u32x4* buf, int ich) {
        const u16* cbA   = cb + (wave_m * 64 + l31) * 128 + ich * 32 + h2 * 8;
        const int  wbase = wave_w * 32 + l31;
        #pragma unroll
        for (int kw = 0; kw < 5; ++kw) {
            const int wp  = wbase + kw;                  // stage column (incl. halo)
            const int vsw = (wp >> 1) & 3;
            const int cb0 = wp << 2;
            #pragma unroll
            for (int kk = 0; kk < 2; ++kk) {
                bf16x8 A[5][2];                          // [kh][oc 32-half]
                #pragma unroll
                for (int kh = 0; kh < 5; ++kh) {
                    const u16* cp = cbA + (kh * 5 + kw) * 16384 + kk * 16;
                    A[kh][0] = *reinterpret_cast<const bf16x8*>(cp);
                    A[kh][1] = *reinterpret_cast<const bf16x8*>(cp + 4096);
                }
                const int cidx = cb0 + ((kk * 2 + h2) ^ vsw);
                __builtin_amdgcn_s_setprio(1);
                #pragma unroll
                for (int rp = 0; rp < 8; ++rp) {
                    const bf16x8 b = __builtin_bit_cast(bf16x8, buf[rp * 528 + cidx]);
                    #pragma unroll
                    for (int kh = 0; kh < 5; ++kh) {
                        const int n = rp - kh;           // output row
                        if (0 <= n && n < 4) {
                            acc[0][n] = __builtin_amdgcn_mfma_f32_32x32x16_bf16(A[kh][0], b, acc[0][n], 0, 0, 0);
                            acc[1][n] = __builtin_amdgcn_mfma_f32_32x32x16_bf16(A[kh][1], b, acc[1][n], 0, 0, 0);
                        }
                    }
                }
                __builtin_amdgcn_s_setprio(0);
            }
        }
    };

    // prologue
    ISSUE(0);
    WRITE(lds4);
    __syncthreads();

    #pragma unroll 1
    for (int ich = 0; ich < 4; ++ich) {
        if (ich < 3) ISSUE(ich + 1);                     // x loads in flight during compute
        COMPUTE(lds4 + (ich & 1) * 4224, ich);
        if (ich < 3) WRITE(lds4 + ((ich + 1) & 1) * 4224);
        __syncthreads();
    }

    // epilogue: D frag (32x32): col=lane&31 -> w, row=(reg&3)+8*(reg>>2)+4*h2 -> oc
    const int wpix = wave_w * 32 + l31;
    #pragma unroll
    for (int m = 0; m < 2; ++m)
        #pragma unroll
        for (int reg = 0; reg < 16; ++reg) {
            const int oc = wave_m * 64 + m * 32 + (reg & 3) + ((reg >> 2) << 3) + (h2 << 2);
            float* op = out + ((size_t)(bb * 128 + oc) * 128 + h0) * 128 + wpix;
            #pragma unroll
            for (int n = 0; n < 4; ++n)
                op[n * 128] = acc[m][n][reg];
        }
}

extern "C" void kernel_launch(void* const* d_in, const int* in_sizes, int n_in,
                              void* d_out, int out_size, void* d_ws, size_t ws_size,
                              hipStream_t stream)
{
    const float* x    = (const float*)d_in[0];
    const float* wxx  = (const float*)d_in[1];
    const float* wi   = (const float*)d_in[2];
    const float* XX   = (const float*)d_in[3];
    const float* iden = (const float*)d_in[4];
    const int*   ixx  = (const int*)d_in[5];
    const int*   iid  = (const int*)d_in[6];

    u16* cbuf = (u16*)d_ws;                              // 819200 B scratch

    build_c<<<1600, 256, 0, stream>>>(wxx, wi, XX, iden, ixx, iid, cbuf);
    conv_mfma<<<512, 512, 0, stream>>>(x, cbuf, (float*)d_out);
}